// Round 1
// baseline (1232.290 us; speedup 1.0000x reference)
//
#include <hip/hip_runtime.h>
#include <hip/hip_bf16.h>

// Fused MoE model: conv1+relu+pool -> conv2+relu+pool -> gate/topk -> experts -> softmax
// One block per image, 512 threads. All intermediates in LDS; no workspace use.

#define BLOCK 512

__global__ __launch_bounds__(BLOCK, 1)
void moe_fused_kernel(const float* __restrict__ x,    // [B,28,28,1]
                      const float* __restrict__ w1,   // [3,3,1,32] HWIO
                      const float* __restrict__ b1,   // [32]
                      const float* __restrict__ w2,   // [3,3,32,64] HWIO
                      const float* __restrict__ b2,   // [64]
                      const float* __restrict__ gw,   // [1600,5]
                      const float* __restrict__ gb,   // [5]
                      const float* __restrict__ ew,   // [5,1600,10]
                      const float* __restrict__ eb,   // [5,10]
                      float* __restrict__ out)        // [B,10]
{
    __shared__ float xs[784];      // 28x28 input
    __shared__ float w1s[288];     // [3][3][32]
    __shared__ float b1s[32];
    __shared__ float w2s[18432];   // [3][3][32][64]
    __shared__ float b2s[64];
    __shared__ float h1[5408];     // [13][13][32] pooled conv1
    __shared__ float feat[1600];   // [5][5][64] pooled conv2 (= flatten)
    __shared__ float allout[5][10];
    __shared__ float gsm[5];

    const int tid = threadIdx.x;
    const int img = blockIdx.x;

    // ---- stage inputs/weights to LDS (coalesced) ----
    const float* xg = x + img * 784;
    for (int i = tid; i < 784; i += BLOCK) xs[i] = xg[i];
    for (int i = tid; i < 288; i += BLOCK) w1s[i] = w1[i];
    if (tid < 32) b1s[tid] = b1[tid];
    for (int i = tid; i < 18432; i += BLOCK) w2s[i] = w2[i];
    if (tid < 64) b2s[tid] = b2[tid];
    __syncthreads();

    // ---- conv1 (3x3, 1->32, VALID) + relu + 2x2 maxpool -> h1[13,13,32] ----
    // relu(max(a)+b) == max over window of relu(a+b) since relu monotone, bias uniform.
    for (int i = tid; i < 5408; i += BLOCK) {
        const int oc = i & 31;
        const int sp = i >> 5;
        const int px = sp % 13, py = sp / 13;
        float a0 = 0.f, a1 = 0.f, a2 = 0.f, a3 = 0.f;
        #pragma unroll
        for (int ky = 0; ky < 3; ky++) {
            #pragma unroll
            for (int kx = 0; kx < 3; kx++) {
                const float w = w1s[(ky * 3 + kx) * 32 + oc];
                const int r0 = 2 * py + ky, c0 = 2 * px + kx;
                a0 += w * xs[r0 * 28 + c0];
                a1 += w * xs[r0 * 28 + c0 + 1];
                a2 += w * xs[(r0 + 1) * 28 + c0];
                a3 += w * xs[(r0 + 1) * 28 + c0 + 1];
            }
        }
        const float m = fmaxf(fmaxf(a0, a1), fmaxf(a2, a3)) + b1s[oc];
        h1[i] = fmaxf(m, 0.f);
    }
    __syncthreads();

    // ---- conv2 (3x3, 32->64, VALID on 13x13 -> 11x11) + relu + pool -> feat[5,5,64] ----
    // pool windows cover conv rows/cols 0..9 (row/col 10 dropped by VALID pooling)
    for (int i = tid; i < 1600; i += BLOCK) {
        const int oc = i & 63;
        const int sp = i >> 6;
        const int px = sp % 5, py = sp / 5;
        float a0 = 0.f, a1 = 0.f, a2 = 0.f, a3 = 0.f;
        #pragma unroll
        for (int ky = 0; ky < 3; ky++) {
            #pragma unroll
            for (int kx = 0; kx < 3; kx++) {
                const int hb = ((2 * py + ky) * 13 + (2 * px + kx)) * 32;
                const float* wrow = &w2s[((ky * 3 + kx) * 32) * 64 + oc];
                #pragma unroll 8
                for (int ic = 0; ic < 32; ic++) {
                    const float w = wrow[ic * 64];
                    a0 += w * h1[hb + ic];            // (cy, cx)
                    a1 += w * h1[hb + 32 + ic];       // (cy, cx+1)
                    a2 += w * h1[hb + 416 + ic];      // (cy+1, cx)   416 = 13*32
                    a3 += w * h1[hb + 448 + ic];      // (cy+1, cx+1)
                }
            }
        }
        const float m = fmaxf(fmaxf(a0, a1), fmaxf(a2, a3)) + b2s[oc];
        feat[i] = fmaxf(m, 0.f);   // feat index == (py*5+px)*64+oc == NHWC flatten
    }
    __syncthreads();

    // ---- gate + expert matmuls (per-wave dot products) ----
    const int wid = tid >> 6;
    const int lane = tid & 63;
    if (wid < 5) {
        // expert `wid`: out[c] = sum_d feat[d] * ew[wid,d,c]  (c=0..9)
        const float* ewp = ew + wid * 16000;
        float acc[10];
        #pragma unroll
        for (int c = 0; c < 10; c++) acc[c] = 0.f;
        for (int d = lane; d < 1600; d += 64) {
            const float f = feat[d];
            const float* wr = ewp + d * 10;
            #pragma unroll
            for (int c = 0; c < 10; c++) acc[c] += f * wr[c];
        }
        #pragma unroll
        for (int c = 0; c < 10; c++) {
            for (int off = 32; off; off >>= 1)
                acc[c] += __shfl_down(acc[c], off);
        }
        if (lane == 0) {
            #pragma unroll
            for (int c = 0; c < 10; c++) allout[wid][c] = acc[c] + eb[wid * 10 + c];
        }
    } else if (wid == 5) {
        // gate logits + softmax
        float acc[5] = {0.f, 0.f, 0.f, 0.f, 0.f};
        for (int d = lane; d < 1600; d += 64) {
            const float f = feat[d];
            const float* wr = gw + d * 5;
            #pragma unroll
            for (int g = 0; g < 5; g++) acc[g] += f * wr[g];
        }
        #pragma unroll
        for (int g = 0; g < 5; g++) {
            for (int off = 32; off; off >>= 1)
                acc[g] += __shfl_down(acc[g], off);
        }
        if (lane == 0) {
            float l[5], mx = -1e30f;
            #pragma unroll
            for (int g = 0; g < 5; g++) { l[g] = acc[g] + gb[g]; mx = fmaxf(mx, l[g]); }
            float s = 0.f;
            #pragma unroll
            for (int g = 0; g < 5; g++) { l[g] = expf(l[g] - mx); s += l[g]; }
            const float inv = 1.f / s;
            #pragma unroll
            for (int g = 0; g < 5; g++) gsm[g] = l[g] * inv;
        }
    }
    __syncthreads();

    // ---- top-3 gather, weighted combine, final softmax (single thread; tiny) ----
    if (tid == 0) {
        float gv[5];
        #pragma unroll
        for (int g = 0; g < 5; g++) gv[g] = gsm[g];
        int idx[3]; float wv[3];
        bool used[5] = {false, false, false, false, false};
        for (int k = 0; k < 3; k++) {
            int bi = 0; float bv = -1e30f;
            for (int g = 0; g < 5; g++)
                if (!used[g] && gv[g] > bv) { bv = gv[g]; bi = g; }  // strict > => lowest idx on tie
            used[bi] = true; idx[k] = bi; wv[k] = bv;
        }
        float comb[10];
        #pragma unroll
        for (int c = 0; c < 10; c++) {
            float s = 0.f;
            for (int k = 0; k < 3; k++) s += wv[k] * allout[idx[k]][c];
            comb[c] = s;
        }
        float mx = -1e30f;
        #pragma unroll
        for (int c = 0; c < 10; c++) mx = fmaxf(mx, comb[c]);
        float e[10], s = 0.f;
        #pragma unroll
        for (int c = 0; c < 10; c++) { e[c] = expf(comb[c] - mx); s += e[c]; }
        const float inv = 1.f / s;
        #pragma unroll
        for (int c = 0; c < 10; c++) out[img * 10 + c] = e[c] * inv;
    }
}

extern "C" void kernel_launch(void* const* d_in, const int* in_sizes, int n_in,
                              void* d_out, int out_size, void* d_ws, size_t ws_size,
                              hipStream_t stream) {
    const float* x   = (const float*)d_in[0];
    const float* w1  = (const float*)d_in[1];
    const float* b1  = (const float*)d_in[2];
    const float* w2  = (const float*)d_in[3];
    const float* b2  = (const float*)d_in[4];
    const float* gw  = (const float*)d_in[5];
    const float* gb  = (const float*)d_in[6];
    const float* ew  = (const float*)d_in[7];
    const float* eb  = (const float*)d_in[8];
    float* out = (float*)d_out;

    const int B = in_sizes[0] / 784;   // 8192
    moe_fused_kernel<<<B, BLOCK, 0, stream>>>(x, w1, b1, w2, b2, gw, gb, ew, eb, out);
}

// Round 2
// 201.623 us; speedup vs baseline: 6.1119x; 6.1119x over previous
//
#include <hip/hip_runtime.h>
#include <hip/hip_bf16.h>

#define BLOCK 512
#define IPB 16   // images per block (2 chunks of 8)

typedef __attribute__((ext_vector_type(8))) short short8;
typedef __attribute__((ext_vector_type(4))) float f32x4;

static __device__ __forceinline__ unsigned short f2bf(float f) {
    unsigned int u = __builtin_bit_cast(unsigned int, f);
    u = (u + 0x7FFFu + ((u >> 16) & 1u)) >> 16;   // RNE
    return (unsigned short)u;
}
static __device__ __forceinline__ float bf2f(unsigned short h) {
    unsigned int u = ((unsigned int)h) << 16;
    return __builtin_bit_cast(float, u);
}

// ---------------- prep kernel: build bf16 weight layouts in d_ws ----------------
// ws[0 .. 18432)            : w2t [kpos=9][oc=64][ic=32] bf16
// ws[18432 .. 18432+102400) : ewt [ks=50][n=64][k=32] bf16 (n<50 experts, 50..54 gate, rest 0)
__global__ void moe_prep(const float* __restrict__ w2, const float* __restrict__ gw,
                         const float* __restrict__ ew, unsigned short* __restrict__ ws) {
    int i = blockIdx.x * 256 + threadIdx.x;
    if (i < 18432) {
        int kpos = i >> 11, rem = i & 2047, oc = rem >> 5, ic = rem & 31;
        ws[i] = f2bf(w2[(kpos * 32 + ic) * 64 + oc]);
    }
    int j = i - 18432;
    if (j >= 0 && j < 102400) {
        int ks = j >> 11, rem = j & 2047, n = rem >> 5, k = rem & 31;
        int d = ks * 32 + k;
        float v = 0.f;
        if (n < 50)      v = ew[(n / 10) * 16000 + d * 10 + (n % 10)];
        else if (n < 55) v = gw[d * 5 + (n - 50)];
        ws[18432 + j] = f2bf(v);
    }
}

// ---------------- main fused kernel ----------------
__global__ __launch_bounds__(BLOCK, 4)
void moe_main(const float* __restrict__ x, const float* __restrict__ w1,
              const float* __restrict__ b1, const float* __restrict__ b2,
              const float* __restrict__ gb, const float* __restrict__ eb,
              const unsigned short* __restrict__ ws, float* __restrict__ out, int B)
{
    __shared__ __align__(16) unsigned short w2t[18432];    // 36864 B
    __shared__ __align__(16) unsigned short featbuf[12800];// 8 imgs x 1600, 25600 B
    __shared__ __align__(16) unsigned short h1p[6760];     // [169 pos][40] bf16, 13520 B
    __shared__ __align__(16) unsigned short xsb[784];      // 1568 B
    __shared__ float w1s[288];                             // 1152 B
    __shared__ float b1s[32];
    __shared__ float b2s[64];
    __shared__ float allC[448];                            // [8 img][56]

    const int tid  = threadIdx.x;
    const int wid  = tid >> 6;
    const int lane = tid & 63;
    const int l15  = lane & 15;
    const int lg   = lane >> 4;

    // -------- per-block setup --------
    {
        const uint4* src = (const uint4*)ws;
        uint4* dst = (uint4*)w2t;
        for (int i = tid; i < 2304; i += BLOCK) dst[i] = src[i];
    }
    for (int i = tid; i < 288; i += BLOCK) w1s[i] = w1[i];
    if (tid < 32) b1s[tid] = b1[tid];
    if (tid < 64) b2s[tid] = b2[tid];
    __syncthreads();

    const int nt = wid & 3;   // N-tile (16 oc) this wave owns for conv2
    const int mh = wid >> 2;  // M-half

    short8 bfrag[9];          // conv2 B fragments, persistent in registers
    #pragma unroll
    for (int kp = 0; kp < 9; kp++)
        bfrag[kp] = *(const short8*)&w2t[(kp * 64 + nt * 16 + l15) * 32 + lg * 8];

    const unsigned short* ewt = ws + 18432;

    for (int c = 0; c < 2; ++c) {
        for (int it = 0; it < 8; ++it) {
            const int img  = blockIdx.x * IPB + c * 8 + it;
            const int imgr = img < B ? img : B - 1;

            // -------- stage x (fp32 -> bf16 LDS) --------
            const float* xg = x + (size_t)imgr * 784;
            for (int i = tid; i < 784; i += BLOCK) xsb[i] = f2bf(xg[i]);
            __syncthreads();

            // -------- conv1 + relu + pool -> h1p[169][40] bf16 --------
            // item = (pooled pos, oc-group of 4); thread: g = tid&7, pos = tid>>3
            {
                const int g = tid & 7;
                #pragma unroll
                for (int round = 0; round < 3; ++round) {
                    const int pidx = round * 64 + (tid >> 3);
                    if (pidx < 169) {
                        const int py = pidx / 13, px = pidx % 13;
                        float xr[4][4];
                        #pragma unroll
                        for (int r = 0; r < 4; r++) {
                            const int base = (2 * py + r) * 28 + 2 * px;
                            unsigned int u0 = *(const unsigned int*)&xsb[base];
                            unsigned int u1 = *(const unsigned int*)&xsb[base + 2];
                            xr[r][0] = bf2f((unsigned short)u0);
                            xr[r][1] = bf2f((unsigned short)(u0 >> 16));
                            xr[r][2] = bf2f((unsigned short)u1);
                            xr[r][3] = bf2f((unsigned short)(u1 >> 16));
                        }
                        float acc[4][4];
                        #pragma unroll
                        for (int wdw = 0; wdw < 4; wdw++)
                            #pragma unroll
                            for (int j = 0; j < 4; j++) acc[wdw][j] = 0.f;
                        #pragma unroll
                        for (int ky = 0; ky < 3; ky++) {
                            #pragma unroll
                            for (int kx = 0; kx < 3; kx++) {
                                const float4 w4 = *(const float4*)&w1s[(ky * 3 + kx) * 32 + g * 4];
                                #pragma unroll
                                for (int wy = 0; wy < 2; wy++) {
                                    #pragma unroll
                                    for (int wx = 0; wx < 2; wx++) {
                                        const float xv = xr[wy + ky][wx + kx];
                                        acc[wy * 2 + wx][0] += w4.x * xv;
                                        acc[wy * 2 + wx][1] += w4.y * xv;
                                        acc[wy * 2 + wx][2] += w4.z * xv;
                                        acc[wy * 2 + wx][3] += w4.w * xv;
                                    }
                                }
                            }
                        }
                        unsigned short o[4];
                        #pragma unroll
                        for (int j = 0; j < 4; j++) {
                            float m = fmaxf(fmaxf(acc[0][j], acc[1][j]), fmaxf(acc[2][j], acc[3][j]))
                                      + b1s[g * 4 + j];
                            o[j] = f2bf(fmaxf(m, 0.f));
                        }
                        uint2 pk;
                        pk.x = (unsigned int)o[0] | ((unsigned int)o[1] << 16);
                        pk.y = (unsigned int)o[2] | ((unsigned int)o[3] << 16);
                        *(uint2*)&h1p[pidx * 40 + g * 4] = pk;
                    }
                }
            }
            __syncthreads();

            // -------- conv2 implicit-GEMM MFMA + relu + pool -> featbuf[it] --------
            // M=112 (7 tiles): m -> window w = m>>2 (py=w/5,px=w%5), s=m&3 -> conv pos
            for (int mt = mh; mt < 7; mt += 2) {
                const int m = mt * 16 + l15;
                int wsrc = m >> 2; if (wsrc > 24) wsrc = 24;
                const int s = m & 3;
                const int cy = 2 * (wsrc / 5) + (s >> 1);
                const int cx = 2 * (wsrc % 5) + (s & 1);
                short8 afrag[9];
                #pragma unroll
                for (int ky = 0; ky < 3; ky++)
                    #pragma unroll
                    for (int kx = 0; kx < 3; kx++)
                        afrag[ky * 3 + kx] =
                            *(const short8*)&h1p[((cy + ky) * 13 + (cx + kx)) * 40 + lg * 8];
                f32x4 acc = {0.f, 0.f, 0.f, 0.f};
                #pragma unroll
                for (int kp = 0; kp < 9; kp++)
                    acc = __builtin_amdgcn_mfma_f32_16x16x32_bf16(afrag[kp], bfrag[kp], acc, 0, 0, 0);
                // D: col = l15 (oc within tile), row = lg*4+reg -> window wv = mt*4+lg, s=reg
                const int wv = mt * 4 + lg;
                if (wv < 25) {
                    const int oc = nt * 16 + l15;
                    float mx = fmaxf(fmaxf(acc.x, acc.y), fmaxf(acc.z, acc.w)) + b2s[oc];
                    featbuf[it * 1600 + wv * 64 + oc] = f2bf(fmaxf(mx, 0.f));
                }
            }
            __syncthreads();
        } // it

        // -------- experts + gate GEMM: [8 img x 1600] @ [1600 x 55] --------
        if (wid < 4) {
            const int bc = nt * 16 + l15;        // output col
            const int arow = l15 & 7;            // image row (rows 8-15 duplicated)
            f32x4 acc = {0.f, 0.f, 0.f, 0.f};
            for (int ks = 0; ks < 50; ++ks) {
                short8 af = *(const short8*)&featbuf[arow * 1600 + ks * 32 + lg * 8];
                short8 bf = *(const short8*)&ewt[(ks * 64 + bc) * 32 + lg * 8];
                acc = __builtin_amdgcn_mfma_f32_16x16x32_bf16(af, bf, acc, 0, 0, 0);
            }
            if (lane < 32 && bc < 56) {          // rows 0..7 only, cols 0..55
                const int r0 = lg * 4;
                allC[(r0 + 0) * 56 + bc] = acc.x;
                allC[(r0 + 1) * 56 + bc] = acc.y;
                allC[(r0 + 2) * 56 + bc] = acc.z;
                allC[(r0 + 3) * 56 + bc] = acc.w;
            }
        }
        __syncthreads();

        // -------- epilogue: gate softmax, top-3, combine, final softmax --------
        if (tid < 8) {
            const int img = blockIdx.x * IPB + c * 8 + tid;
            if (img < B) {
                float gv[5], mx = -1e30f;
                #pragma unroll
                for (int g = 0; g < 5; g++) {
                    gv[g] = allC[tid * 56 + 50 + g] + gb[g];
                    mx = fmaxf(mx, gv[g]);
                }
                float ssum = 0.f;
                #pragma unroll
                for (int g = 0; g < 5; g++) { gv[g] = expf(gv[g] - mx); ssum += gv[g]; }
                const float inv = 1.f / ssum;
                #pragma unroll
                for (int g = 0; g < 5; g++) gv[g] *= inv;

                int idx[3]; float wv[3];
                bool used[5] = {false, false, false, false, false};
                for (int k = 0; k < 3; k++) {
                    int bi = 0; float bv = -1e30f;
                    for (int g = 0; g < 5; g++)
                        if (!used[g] && gv[g] > bv) { bv = gv[g]; bi = g; }
                    used[bi] = true; idx[k] = bi; wv[k] = bv;
                }
                float comb[10];
                #pragma unroll
                for (int cc = 0; cc < 10; cc++) {
                    float s = 0.f;
                    for (int k = 0; k < 3; k++)
                        s += wv[k] * (allC[tid * 56 + idx[k] * 10 + cc] + eb[idx[k] * 10 + cc]);
                    comb[cc] = s;
                }
                float m2 = -1e30f;
                #pragma unroll
                for (int cc = 0; cc < 10; cc++) m2 = fmaxf(m2, comb[cc]);
                float e[10], s2 = 0.f;
                #pragma unroll
                for (int cc = 0; cc < 10; cc++) { e[cc] = expf(comb[cc] - m2); s2 += e[cc]; }
                const float inv2 = 1.f / s2;
                #pragma unroll
                for (int cc = 0; cc < 10; cc++) out[(size_t)img * 10 + cc] = e[cc] * inv2;
            }
        }
        __syncthreads();
    } // c
}

// ---------------- fallback (round-1 kernel, used only if ws too small) ----------------
__global__ __launch_bounds__(BLOCK, 1)
void moe_fused_fallback(const float* __restrict__ x, const float* __restrict__ w1,
                        const float* __restrict__ b1, const float* __restrict__ w2,
                        const float* __restrict__ b2, const float* __restrict__ gw,
                        const float* __restrict__ gb, const float* __restrict__ ew,
                        const float* __restrict__ eb, float* __restrict__ out)
{
    __shared__ float xs[784];
    __shared__ float w1s[288];
    __shared__ float b1s[32];
    __shared__ float w2s[18432];
    __shared__ float b2s[64];
    __shared__ float h1[5408];
    __shared__ float feat[1600];
    __shared__ float allout[5][10];
    __shared__ float gsm[5];

    const int tid = threadIdx.x;
    const int img = blockIdx.x;
    const float* xg = x + img * 784;
    for (int i = tid; i < 784; i += BLOCK) xs[i] = xg[i];
    for (int i = tid; i < 288; i += BLOCK) w1s[i] = w1[i];
    if (tid < 32) b1s[tid] = b1[tid];
    for (int i = tid; i < 18432; i += BLOCK) w2s[i] = w2[i];
    if (tid < 64) b2s[tid] = b2[tid];
    __syncthreads();

    for (int i = tid; i < 5408; i += BLOCK) {
        const int oc = i & 31, sp = i >> 5, px = sp % 13, py = sp / 13;
        float a0 = 0.f, a1 = 0.f, a2 = 0.f, a3 = 0.f;
        #pragma unroll
        for (int ky = 0; ky < 3; ky++)
            #pragma unroll
            for (int kx = 0; kx < 3; kx++) {
                const float w = w1s[(ky * 3 + kx) * 32 + oc];
                const int r0 = 2 * py + ky, c0 = 2 * px + kx;
                a0 += w * xs[r0 * 28 + c0];     a1 += w * xs[r0 * 28 + c0 + 1];
                a2 += w * xs[(r0 + 1) * 28 + c0]; a3 += w * xs[(r0 + 1) * 28 + c0 + 1];
            }
        h1[i] = fmaxf(fmaxf(fmaxf(a0, a1), fmaxf(a2, a3)) + b1s[oc], 0.f);
    }
    __syncthreads();

    for (int i = tid; i < 1600; i += BLOCK) {
        const int oc = i & 63, sp = i >> 6, px = sp % 5, py = sp / 5;
        float a0 = 0.f, a1 = 0.f, a2 = 0.f, a3 = 0.f;
        #pragma unroll
        for (int ky = 0; ky < 3; ky++)
            #pragma unroll
            for (int kx = 0; kx < 3; kx++) {
                const int hb = ((2 * py + ky) * 13 + (2 * px + kx)) * 32;
                const float* wrow = &w2s[((ky * 3 + kx) * 32) * 64 + oc];
                #pragma unroll 8
                for (int ic = 0; ic < 32; ic++) {
                    const float w = wrow[ic * 64];
                    a0 += w * h1[hb + ic];      a1 += w * h1[hb + 32 + ic];
                    a2 += w * h1[hb + 416 + ic]; a3 += w * h1[hb + 448 + ic];
                }
            }
        feat[i] = fmaxf(fmaxf(fmaxf(a0, a1), fmaxf(a2, a3)) + b2s[oc], 0.f);
    }
    __syncthreads();

    const int wid = tid >> 6, lane = tid & 63;
    if (wid < 5) {
        const float* ewp = ew + wid * 16000;
        float acc[10];
        #pragma unroll
        for (int cidx = 0; cidx < 10; cidx++) acc[cidx] = 0.f;
        for (int d = lane; d < 1600; d += 64) {
            const float f = feat[d]; const float* wr = ewp + d * 10;
            #pragma unroll
            for (int cidx = 0; cidx < 10; cidx++) acc[cidx] += f * wr[cidx];
        }
        #pragma unroll
        for (int cidx = 0; cidx < 10; cidx++)
            for (int off = 32; off; off >>= 1) acc[cidx] += __shfl_down(acc[cidx], off);
        if (lane == 0)
            #pragma unroll
            for (int cidx = 0; cidx < 10; cidx++) allout[wid][cidx] = acc[cidx] + eb[wid * 10 + cidx];
    } else if (wid == 5) {
        float acc[5] = {0.f, 0.f, 0.f, 0.f, 0.f};
        for (int d = lane; d < 1600; d += 64) {
            const float f = feat[d]; const float* wr = gw + d * 5;
            #pragma unroll
            for (int g = 0; g < 5; g++) acc[g] += f * wr[g];
        }
        #pragma unroll
        for (int g = 0; g < 5; g++)
            for (int off = 32; off; off >>= 1) acc[g] += __shfl_down(acc[g], off);
        if (lane == 0) {
            float l[5], mx = -1e30f;
            #pragma unroll
            for (int g = 0; g < 5; g++) { l[g] = acc[g] + gb[g]; mx = fmaxf(mx, l[g]); }
            float s = 0.f;
            #pragma unroll
            for (int g = 0; g < 5; g++) { l[g] = expf(l[g] - mx); s += l[g]; }
            const float inv = 1.f / s;
            #pragma unroll
            for (int g = 0; g < 5; g++) gsm[g] = l[g] * inv;
        }
    }
    __syncthreads();

    if (tid == 0) {
        float gv[5];
        #pragma unroll
        for (int g = 0; g < 5; g++) gv[g] = gsm[g];
        int idx[3]; float wv[3];
        bool used[5] = {false, false, false, false, false};
        for (int k = 0; k < 3; k++) {
            int bi = 0; float bv = -1e30f;
            for (int g = 0; g < 5; g++)
                if (!used[g] && gv[g] > bv) { bv = gv[g]; bi = g; }
            used[bi] = true; idx[k] = bi; wv[k] = bv;
        }
        float comb[10];
        #pragma unroll
        for (int cc = 0; cc < 10; cc++) {
            float s = 0.f;
            for (int k = 0; k < 3; k++) s += wv[k] * allout[idx[k]][cc];
            comb[cc] = s;
        }
        float mx = -1e30f;
        #pragma unroll
        for (int cc = 0; cc < 10; cc++) mx = fmaxf(mx, comb[cc]);
        float e[10], s = 0.f;
        #pragma unroll
        for (int cc = 0; cc < 10; cc++) { e[cc] = expf(comb[cc] - mx); s += e[cc]; }
        const float inv = 1.f / s;
        #pragma unroll
        for (int cc = 0; cc < 10; cc++) out[img * 10 + cc] = e[cc] * inv;
    }
}

extern "C" void kernel_launch(void* const* d_in, const int* in_sizes, int n_in,
                              void* d_out, int out_size, void* d_ws, size_t ws_size,
                              hipStream_t stream) {
    const float* x   = (const float*)d_in[0];
    const float* w1  = (const float*)d_in[1];
    const float* b1  = (const float*)d_in[2];
    const float* w2  = (const float*)d_in[3];
    const float* b2  = (const float*)d_in[4];
    const float* gw  = (const float*)d_in[5];
    const float* gb  = (const float*)d_in[6];
    const float* ew  = (const float*)d_in[7];
    const float* eb  = (const float*)d_in[8];
    float* out = (float*)d_out;
    const int B = in_sizes[0] / 784;

    const size_t WS_NEEDED = (18432 + 102400) * sizeof(unsigned short);
    if (ws_size >= WS_NEEDED) {
        unsigned short* ws = (unsigned short*)d_ws;
        moe_prep<<<472, 256, 0, stream>>>(w2, gw, ew, ws);
        const int nblk = (B + IPB - 1) / IPB;
        moe_main<<<nblk, BLOCK, 0, stream>>>(x, w1, b1, b2, gb, eb, ws, out, B);
    } else {
        moe_fused_fallback<<<B, BLOCK, 0, stream>>>(x, w1, b1, w2, b2, gw, gb, ew, eb, out);
    }
}